// Round 13
// baseline (178.714 us; speedup 1.0000x reference)
//
#include <hip/hip_runtime.h>
#include <math.h>

#define CAT    134
#define NRBF   6
#define ADIM   42
#define NBIL   8
#define KPAD   144      // 9 k-steps of 16 (k=134 is the bias column)
#define CHPAD  160      // 5 groups x 32 channels
#define MSTR   152      // m LDS row stride (shorts): 304 B, 16B-aligned
#define TSTR   168      // mae row stride (shorts): 336 B, 16B-aligned
#define TE     32       // edges per tile
#define M2     (TE * 67)   // float2 count of one m tile (32*134/2)

typedef __bf16 bf16x8 __attribute__((ext_vector_type(8)));
typedef float  f32x16 __attribute__((ext_vector_type(16)));
typedef float  f32x4  __attribute__((ext_vector_type(4)));

__device__ __forceinline__ unsigned short f32_bf16_rne(float x) {
    union { float f; unsigned u; } v; v.f = x;
    unsigned u = v.u;
    u += 0x7FFFu + ((u >> 16) & 1u);
    return (unsigned short)(u >> 16);
}
__device__ __forceinline__ float bf16_f32(unsigned short h) {
    union { float f; unsigned u; } v; v.u = ((unsigned)h) << 16;
    return v.f;
}
// trunc split: a = hi + lo, |err| ~ 2^-17 |a|
__device__ __forceinline__ void split_pack(float a, float b, unsigned& ph, unsigned& pl) {
    unsigned ua = __float_as_uint(a), ub = __float_as_uint(b);
    ph = (ua >> 16) | (ub & 0xffff0000u);
    float ra = a - __uint_as_float(ua & 0xffff0000u);
    float rb = b - __uint_as_float(ub & 0xffff0000u);
    pl = (__float_as_uint(ra) >> 16) | (__float_as_uint(rb) & 0xffff0000u);
}
__device__ __forceinline__ bf16x8 upack(unsigned a, unsigned b, unsigned c, unsigned d) {
    union { unsigned u[4]; bf16x8 v; } t;
    t.u[0] = a; t.u[1] = b; t.u[2] = c; t.u[3] = d;
    return t.v;
}

// ---------------------------------------------------------------------------
// prep: pack weights into FRAGMENT-MAJOR layout (5 groups incl. tail group 4)
// ---------------------------------------------------------------------------
__global__ __launch_bounds__(256) void prep_kernel(
    const float* __restrict__ Wm, const float* __restrict__ bm,
    const float* __restrict__ We, const float* __restrict__ fw,
    unsigned short* __restrict__ WF, unsigned short* __restrict__ WeF,
    unsigned short* __restrict__ FwF)
{
    int i = blockIdx.x * 256 + threadIdx.x;
    if (i < CHPAD * KPAD) {                                  // W_m (+bias col)
        int c = i / KPAD, k = i - c * KPAD;
        float v = 0.f;
        if (c < CAT) {
            if (k < CAT) v = Wm[c * CAT + k];
            else if (k == CAT) v = bm[c];
        }
        unsigned short h = f32_bf16_rne(v);
        unsigned short l = f32_bf16_rne(v - bf16_f32(h));
        int wv = c >> 5, l31 = c & 31, ks = k >> 4;
        int lane = ((k >> 3) & 1) * 32 + l31, j = k & 7;
        size_t idx = ((size_t)(wv * 9 + ks) * 64 + lane) * 16 + j;
        WF[idx] = h; WF[idx + 8] = l;
    } else if (i < CHPAD * KPAD + CHPAD * 16) {              // W_e (K -> 16)
        int j2 = i - CHPAD * KPAD; int c = j2 >> 4, r = j2 & 15;
        float v = (c < CAT && r < NRBF) ? We[c * NRBF + r] : 0.f;
        unsigned short h = f32_bf16_rne(v);
        unsigned short l = f32_bf16_rne(v - bf16_f32(h));
        int wv = c >> 5, l31 = c & 31;
        int lane = (r >> 3) * 32 + l31, j = r & 7;
        size_t idx = ((size_t)wv * 64 + lane) * 16 + j;
        WeF[idx] = h; WeF[idx + 8] = l;
    } else if (i < CHPAD * KPAD + CHPAD * 16 + 16 * CHPAD) { // final_w (16 rows)
        int j3 = i - CHPAD * KPAD - CHPAD * 16;
        int r = j3 / CHPAD, c = j3 - r * CHPAD;
        float v = (r < NRBF && c < CAT) ? fw[r * CAT + c] : 0.f;
        unsigned short h = f32_bf16_rne(v);
        unsigned short l = f32_bf16_rne(v - bf16_f32(h));
        int wv = c >> 5, kk = c & 31;
        int lane = (kk >> 3) * 16 + r, j = kk & 7;
        size_t idx = ((size_t)wv * 64 + lane) * 16 + j;
        FwF[idx] = h; FwF[idx + 8] = l;
    }
}

// ---------------------------------------------------------------------------
// angle: s_a = dot(a_sbf[a,:], colsum(W_a)), scatter-add into sum_s[kj]
// ---------------------------------------------------------------------------
__global__ __launch_bounds__(256) void angle_kernel(
    const float* __restrict__ a_sbf, const int* __restrict__ kj_idx,
    const float* __restrict__ W_a, float* __restrict__ sum_s, int A)
{
    __shared__ float wsum[ADIM];
    int tid = threadIdx.x;
    if (tid < ADIM) {
        float s = 0.f;
        #pragma unroll
        for (int b = 0; b < NBIL; ++b) s += W_a[b * ADIM + tid];
        wsum[tid] = s;
    }
    __syncthreads();

    int a = blockIdx.x * 256 + tid;
    if (a >= A) return;

    const float* row = a_sbf + (size_t)a * ADIM;
    float s = 0.f;
    #pragma unroll
    for (int d2 = 0; d2 < ADIM / 2; ++d2) {
        float2 v = *reinterpret_cast<const float2*>(row + d2 * 2);
        s += v.x * wsum[d2 * 2] + v.y * wsum[d2 * 2 + 1];
    }
    atomicAdd(&sum_s[kj_idx[a]], s);
}

// Zero-instruction opaque pin (R7-validated), extended with tail A-frags.
#define PIN_WEIGHTS()                                                          \
    asm volatile("" :                                                         \
        "+v"(wfh[0]), "+v"(wfh[1]), "+v"(wfh[2]), "+v"(wfh[3]), "+v"(wfh[4]), \
        "+v"(wfh[5]), "+v"(wfh[6]), "+v"(wfh[7]), "+v"(wfh[8]),               \
        "+v"(wfl[0]), "+v"(wfl[1]), "+v"(wfl[2]), "+v"(wfl[3]), "+v"(wfl[4]), \
        "+v"(wfl[5]), "+v"(wfl[6]), "+v"(wfl[7]), "+v"(wfl[8]),               \
        "+v"(weh), "+v"(wel), "+v"(fwh), "+v"(fwl),                           \
        "+v"(a4h[0]), "+v"(a4h[1]), "+v"(a4h[2]),                             \
        "+v"(a4l[0]), "+v"(a4l[1]), "+v"(a4l[2]))

// ---------------------------------------------------------------------------
// edge: 32-edge tiles, 4 waves (2 blocks/CU). Tail group-4 MFMA1 DISTRIBUTED:
// wave wv computes the tail K-partial for its own k-steps inline in the main
// ks loop (reusing the SAME B-frags it already loaded) into an independent
// acc4 chain; partials land in a 4KB LDS buffer. Post-barrier a rotating wave
// finishes the tail in VALU (sum, silu, te4, shfl, 36 FMA) and atomicAdds
// proj_tail to out; reducers atomicAdd the 4 main groups. out pre-zeroed
// in-graph. 2 barriers/tile.
// ---------------------------------------------------------------------------
__global__ __launch_bounds__(256, 2) void edge_kernel(
    const float* __restrict__ m_ji, const float* __restrict__ e_rbf,
    const float* __restrict__ We_raw, const float* __restrict__ Fw_raw,
    const unsigned short* __restrict__ WF, const unsigned short* __restrict__ WeF,
    const unsigned short* __restrict__ FwF,
    const float* __restrict__ sum_s, float* __restrict__ out, int E, int NT)
{
    __shared__ unsigned short mhs[TE][MSTR];    //  9728 B
    __shared__ unsigned short mls[TE][MSTR];    //  9728 B
    __shared__ unsigned short maeh[TE][TSTR];   // 10752 B (proj overlaid)
    __shared__ unsigned short mael[TE][TSTR];   // 10752 B
    __shared__ float tailp[4][64][4];           //  4096 B  -> 45056 B total

    const int tid = threadIdx.x;
    const int l   = tid & 63;
    const int wv  = __builtin_amdgcn_readfirstlane(tid >> 6);  // 0..3
    const int l31 = l & 31;
    const int hi5 = l >> 5;
    const int GD  = gridDim.x;

    // ---- resident weight fragments for this wave's main group ------------
    bf16x8 wfh[9], wfl[9];
    #pragma unroll
    for (int ks = 0; ks < 9; ++ks) {
        const unsigned short* p = WF + ((size_t)(wv * 9 + ks) * 64 + l) * 16;
        wfh[ks] = *reinterpret_cast<const bf16x8*>(p);
        wfl[ks] = *reinterpret_cast<const bf16x8*>(p + 8);
    }
    const unsigned short* pe = WeF + ((size_t)wv * 64 + l) * 16;
    bf16x8 weh = *reinterpret_cast<const bf16x8*>(pe);
    bf16x8 wel = *reinterpret_cast<const bf16x8*>(pe + 8);
    const unsigned short* pf = FwF + ((size_t)wv * 64 + l) * 16;
    bf16x8 fwh = *reinterpret_cast<const bf16x8*>(pf);
    bf16x8 fwl = *reinterpret_cast<const bf16x8*>(pf + 8);

    // ---- resident tail A-frags for this wave's tail k-steps --------------
    const int kb  = (wv == 3) ? 6 : 2 * wv;   // tail ks base
    bf16x8 a4h[3], a4l[3];
    #pragma unroll
    for (int j = 0; j < 3; ++j) {
        int ksx = kb + j; if (ksx > 8) ksx = 8;
        const unsigned short* p4 = WF + ((size_t)(4 * 9 + ksx) * 64 + l) * 16;
        a4h[j] = *reinterpret_cast<const bf16x8*>(p4);
        a4l[j] = *reinterpret_cast<const bf16x8*>(p4 + 8);
    }
    PIN_WEIGHTS();

    // ---- wave-uniform scalars: W_e rows 128..133, final_w cols 128..133 --
    float we4[6][6], fw4v[6][6];
    #pragma unroll
    for (int r0 = 0; r0 < 6; ++r0)
        #pragma unroll
        for (int r = 0; r < 6; ++r) {
            we4[r0][r]  = We_raw[(size_t)(128 + r0) * NRBF + r];
            fw4v[r0][r] = Fw_raw[(size_t)r0 * CAT + 128 + r];
        }

    // ---- one-time LDS init: m bias/pad cols 134..143 ---------------------
    if (tid < 160) {
        int r = tid / 5, j = tid - r * 5;
        *reinterpret_cast<unsigned*>(&mhs[r][134 + 2 * j]) = (j == 0) ? 0x00003F80u : 0u;
        *reinterpret_cast<unsigned*>(&mls[r][134 + 2 * j]) = 0u;
    }

    // ---- per-lane prefetch state -----------------------------------------
    float2 mpre[9];
    float2 er01, er23, er45;
    float  ssp;    // reduce-mapped sum_s (tid<192)
    float  ssl;    // lane-mapped sum_s (edge l31) for tail finisher

#define LOADM(T)                                                              \
    do { int tt = (T);                                                        \
        const float2* mb = reinterpret_cast<const float2*>(m_ji + (size_t)tt * TE * CAT); \
        int nv2 = min(TE, E - tt * TE) * 67;                                  \
        _Pragma("unroll")                                                     \
        for (int i_ = 0; i_ < 9; ++i_) {                                      \
            int f_ = tid + i_ * 256;                                          \
            mpre[i_] = (f_ < nv2) ? mb[f_] : make_float2(0.f, 0.f);           \
        }                                                                     \
    } while (0)

#define LOADE(T)                                                              \
    do { int tt = (T);                                                        \
        er01 = make_float2(0.f, 0.f); er23 = er01; er45 = er01; ssl = 0.f;    \
        int e_ = tt * TE + l31;                                               \
        if (e_ < E) {                                                         \
            const float* ep_ = e_rbf + (size_t)e_ * NRBF;                     \
            er01 = *reinterpret_cast<const float2*>(ep_);                     \
            er23 = *reinterpret_cast<const float2*>(ep_ + 2);                 \
            er45 = *reinterpret_cast<const float2*>(ep_ + 4);                 \
            ssl  = sum_s[e_];                                                 \
        }                                                                     \
    } while (0)

#define LOADSS(T)                                                             \
    do { int tt = (T);                                                        \
        ssp = 0.f;                                                            \
        if (tid < 192) {                                                      \
            int eo_ = tt * TE + tid / 6;                                      \
            if (eo_ < E) ssp = sum_s[eo_];                                    \
        }                                                                     \
    } while (0)

    // ---- prologue: prefetch tile t0 ---------------------------------------
    {
        int t0 = blockIdx.x;
        LOADM(t0); LOADE(t0); LOADSS(t0);
    }

    int it = 0;
    for (int t = blockIdx.x; t < NT; t += GD, ++it) {
        const int e0 = t * TE;
        PIN_WEIGHTS();

        // ---- latch this tile's er/ss; build eb frags ---------------------
        float er_s0 = er01.x, er_s1 = er01.y, er_s2 = er23.x,
              er_s3 = er23.y, er_s4 = er45.x, er_s5 = er45.y;
        const float ss_cur = ssp;
        const float ssl_cur = ssl;
        bf16x8 ebh, ebl;
        {
            unsigned h0, h1, h2, q0, q1, q2;
            split_pack(er01.x, er01.y, h0, q0);
            split_pack(er23.x, er23.y, h1, q1);
            split_pack(er45.x, er45.y, h2, q2);
            if (hi5) { h0 = h1 = h2 = q0 = q1 = q2 = 0; }   // k 8..15 pad
            ebh = upack(h0, h1, h2, 0);
            ebl = upack(q0, q1, q2, 0);
        }

        // ---- stage m tile -> split-bf16 LDS (once per value) -------------
        #pragma unroll
        for (int i = 0; i < 9; ++i) {
            int f = tid + i * 256;
            if (f < M2) {
                int r = f / 67, c = f - r * 67;
                unsigned h, lo2; split_pack(mpre[i].x, mpre[i].y, h, lo2);
                *reinterpret_cast<unsigned*>(&mhs[r][2 * c]) = h;
                *reinterpret_cast<unsigned*>(&mls[r][2 * c]) = lo2;
            }
        }
        __syncthreads();   // barrier A: tile staged

        // ---- issue next tile's global loads (ride under MFMA) ------------
        if (t + GD < NT) { LOADM(t + GD); LOADE(t + GD); LOADSS(t + GD); }

        // ---- MFMA1 main + inline tail K-partial (independent chains) -----
        f32x16 acc  = {0,0,0,0,0,0,0,0,0,0,0,0,0,0,0,0};
        f32x16 acct = {0,0,0,0,0,0,0,0,0,0,0,0,0,0,0,0};
        f32x16 acc4 = {0,0,0,0,0,0,0,0,0,0,0,0,0,0,0,0};
        #pragma unroll
        for (int ks = 0; ks < 9; ++ks) {
            bf16x8 bh = *reinterpret_cast<const bf16x8*>(&mhs[l31][ks * 16 + hi5 * 8]);
            bf16x8 bl = *reinterpret_cast<const bf16x8*>(&mls[l31][ks * 16 + hi5 * 8]);
            acc = __builtin_amdgcn_mfma_f32_32x32x16_bf16(wfh[ks], bh, acc, 0, 0, 0);
            acc = __builtin_amdgcn_mfma_f32_32x32x16_bf16(wfl[ks], bh, acc, 0, 0, 0);
            acc = __builtin_amdgcn_mfma_f32_32x32x16_bf16(wfh[ks], bl, acc, 0, 0, 0);
            if (ks == kb) {
                acc4 = __builtin_amdgcn_mfma_f32_32x32x16_bf16(a4h[0], bh, acc4, 0, 0, 0);
                acc4 = __builtin_amdgcn_mfma_f32_32x32x16_bf16(a4l[0], bh, acc4, 0, 0, 0);
                acc4 = __builtin_amdgcn_mfma_f32_32x32x16_bf16(a4h[0], bl, acc4, 0, 0, 0);
            } else if (ks == kb + 1) {
                acc4 = __builtin_amdgcn_mfma_f32_32x32x16_bf16(a4h[1], bh, acc4, 0, 0, 0);
                acc4 = __builtin_amdgcn_mfma_f32_32x32x16_bf16(a4l[1], bh, acc4, 0, 0, 0);
                acc4 = __builtin_amdgcn_mfma_f32_32x32x16_bf16(a4h[1], bl, acc4, 0, 0, 0);
            } else if (wv == 3 && ks == 8) {
                acc4 = __builtin_amdgcn_mfma_f32_32x32x16_bf16(a4h[2], bh, acc4, 0, 0, 0);
                acc4 = __builtin_amdgcn_mfma_f32_32x32x16_bf16(a4l[2], bh, acc4, 0, 0, 0);
                acc4 = __builtin_amdgcn_mfma_f32_32x32x16_bf16(a4h[2], bl, acc4, 0, 0, 0);
            }
        }
        acct = __builtin_amdgcn_mfma_f32_32x32x16_bf16(weh, ebh, acct, 0, 0, 0);
        acct = __builtin_amdgcn_mfma_f32_32x32x16_bf16(wel, ebh, acct, 0, 0, 0);
        acct = __builtin_amdgcn_mfma_f32_32x32x16_bf16(weh, ebl, acct, 0, 0, 0);

        // ---- write tail K-partial (rows 0-3 / 4-5 of x_tail) -------------
        {
            f32x4 tp; tp[0] = acc4[0]; tp[1] = acc4[1]; tp[2] = acc4[2]; tp[3] = acc4[3];
            *reinterpret_cast<f32x4*>(&tailp[wv][l][0]) = tp;
        }

        // ---- mae main = silu(x)*te -> wave-private LDS slice -------------
        #pragma unroll
        for (int q = 0; q < 4; ++q) {
            float mz[4];
            #pragma unroll
            for (int i = 0; i < 4; ++i) {
                float x  = acc[q * 4 + i];
                float sg = x / (1.f + __expf(-x));
                mz[i] = sg * acct[q * 4 + i];
            }
            unsigned h0, h1, q0, q1;
            split_pack(mz[0], mz[1], h0, q0);
            split_pack(mz[2], mz[3], h1, q1);
            const int cq = 32 * wv + 8 * q + 4 * hi5;
            *reinterpret_cast<uint2*>(&maeh[l31][cq]) = make_uint2(h0, h1);
            *reinterpret_cast<uint2*>(&mael[l31][cq]) = make_uint2(q0, q1);
        }

        // ---- MFMA3 main: own slice -> overlay [es][32wv..] ---------------
        #pragma unroll
        for (int nt = 0; nt < 2; ++nt) {
            f32x4 a3 = {0, 0, 0, 0};
            const int mr = nt * 16 + (l & 15);
            bf16x8 bh = *reinterpret_cast<const bf16x8*>(&maeh[mr][32 * wv + (l >> 4) * 8]);
            bf16x8 bl = *reinterpret_cast<const bf16x8*>(&mael[mr][32 * wv + (l >> 4) * 8]);
            a3 = __builtin_amdgcn_mfma_f32_16x16x32_bf16(fwh, bh, a3, 0, 0, 0);
            a3 = __builtin_amdgcn_mfma_f32_16x16x32_bf16(fwl, bh, a3, 0, 0, 0);
            a3 = __builtin_amdgcn_mfma_f32_16x16x32_bf16(fwh, bl, a3, 0, 0, 0);
            const int g4 = l >> 4, es = nt * 16 + (l & 15);
            if (g4 == 0) {
                *reinterpret_cast<f32x4*>(&maeh[es][32 * wv]) = a3;
            } else if (g4 == 1) {
                *reinterpret_cast<float*>(&maeh[es][32 * wv + 8])  = a3[0];
                *reinterpret_cast<float*>(&maeh[es][32 * wv + 10]) = a3[1];
            }
        }
        __syncthreads();   // barrier B: overlays + tail partials complete

        // ---- reducers: sum 4 main groups, atomicAdd to out ---------------
        if (tid < 192) {
            const int es = tid / 6, r = tid - es * 6;
            const int eo = e0 + es;
            if (eo < E) {
                float vsum = 0.f;
                #pragma unroll
                for (int w2 = 0; w2 < 4; ++w2)
                    vsum += *reinterpret_cast<const float*>(&maeh[es][32 * w2 + 2 * r]);
                atomicAdd(&out[(size_t)eo * NRBF + r], vsum * ss_cur);
            }
        }

        // ---- tail finisher (rotating wave): VALU + atomics ---------------
        if (wv == ((blockIdx.x + it) & 3)) {
            f32x4 s0 = *reinterpret_cast<const f32x4*>(&tailp[0][l][0]);
            f32x4 s1 = *reinterpret_cast<const f32x4*>(&tailp[1][l][0]);
            f32x4 s2 = *reinterpret_cast<const f32x4*>(&tailp[2][l][0]);
            f32x4 s3 = *reinterpret_cast<const f32x4*>(&tailp[3][l][0]);
            float x4[4], te4[4], mae4[4];
            #pragma unroll
            for (int i = 0; i < 4; ++i) x4[i] = s0[i] + s1[i] + s2[i] + s3[i];
            #pragma unroll
            for (int i = 0; i < 4; ++i) {
                float dlo = er_s0 * we4[i][0] + er_s1 * we4[i][1] + er_s2 * we4[i][2]
                          + er_s3 * we4[i][3] + er_s4 * we4[i][4] + er_s5 * we4[i][5];
                float dhi = 0.f;
                if (i < 2)
                    dhi = er_s0 * we4[4 + i][0] + er_s1 * we4[4 + i][1] + er_s2 * we4[4 + i][2]
                        + er_s3 * we4[4 + i][3] + er_s4 * we4[4 + i][4] + er_s5 * we4[4 + i][5];
                te4[i] = hi5 ? dhi : dlo;
            }
            #pragma unroll
            for (int i = 0; i < 4; ++i) {
                float sg = x4[i] / (1.f + __expf(-x4[i]));
                mae4[i] = sg * te4[i];
            }
            // fetch partner-half mae (channels 132,133 live on lanes 32..63)
            float p0 = __shfl(mae4[0], l31 + 32, 64);
            float p1 = __shfl(mae4[1], l31 + 32, 64);
            if (hi5 == 0) {
                const int e = e0 + l31;
                if (e < E) {
                    #pragma unroll
                    for (int r = 0; r < NRBF; ++r) {
                        float pr = fw4v[r][0] * mae4[0] + fw4v[r][1] * mae4[1]
                                 + fw4v[r][2] * mae4[2] + fw4v[r][3] * mae4[3]
                                 + fw4v[r][4] * p0      + fw4v[r][5] * p1;
                        atomicAdd(&out[(size_t)e * NRBF + r], pr * ssl_cur);
                    }
                }
            }
        }
    }
#undef LOADM
#undef LOADE
#undef LOADSS
}

// ---------------------------------------------------------------------------
extern "C" void kernel_launch(void* const* d_in, const int* in_sizes, int n_in,
                              void* d_out, int out_size, void* d_ws, size_t ws_size,
                              hipStream_t stream)
{
    const float* m_ji    = (const float*)d_in[0];
    // d_in[1] nbr_list, d_in[2] angle_list: unused by the reference math
    const float* e_rbf   = (const float*)d_in[3];
    const float* a_sbf   = (const float*)d_in[4];
    const int*   kj_idx  = (const int*)  d_in[5];
    const float* W_m     = (const float*)d_in[6];
    const float* b_m     = (const float*)d_in[7];
    const float* W_e     = (const float*)d_in[8];
    const float* W_a     = (const float*)d_in[9];
    const float* final_w = (const float*)d_in[10];
    float* out = (float*)d_out;

    const int E  = in_sizes[0] / CAT;
    const int A  = in_sizes[5];
    const int NT = (E + TE - 1) / TE;

    // workspace layout
    char* ws = (char*)d_ws;
    float* sum_s = (float*)ws;
    size_t off = ((size_t)E * 4 + 255) & ~(size_t)255;
    unsigned short* WF  = (unsigned short*)(ws + off); off += (size_t)5 * 9 * 64 * 16 * 2;
    unsigned short* WeF = (unsigned short*)(ws + off); off += (size_t)5 * 64 * 16 * 2;
    unsigned short* FwF = (unsigned short*)(ws + off); off += (size_t)5 * 64 * 16 * 2;

    hipMemsetAsync(sum_s, 0, (size_t)E * sizeof(float), stream);
    hipMemsetAsync(out, 0, (size_t)out_size * sizeof(float), stream);  // atomics accumulate into zeroed out

    const int prep_n = CHPAD * KPAD + CHPAD * 16 + 16 * CHPAD;
    prep_kernel<<<(prep_n + 255) / 256, 256, 0, stream>>>(
        W_m, b_m, W_e, final_w, WF, WeF, FwF);
    angle_kernel<<<(A + 255) / 256, 256, 0, stream>>>(a_sbf, kj_idx, W_a, sum_s, A);

    int grid = 2048; if (grid > NT) grid = NT;
    edge_kernel<<<grid, 256, 0, stream>>>(m_ji, e_rbf, W_e, final_w, WF, WeF, FwF,
                                          sum_s, out, E, NT);
}

// Round 14
// 166.453 us; speedup vs baseline: 1.0737x; 1.0737x over previous
//
#include <hip/hip_runtime.h>
#include <math.h>

#define CAT    134
#define NRBF   6
#define ADIM   42
#define NBIL   8
#define KPAD   144      // 9 k-steps of 16 (k=134 is the bias column)
#define CHPAD  160      // 5 groups x 32 channels
#define MSTR   152      // m LDS row stride (shorts): 304 B, 16B-aligned
#define TSTR   168      // mae row stride (shorts): 336 B, 16B-aligned
#define TE     32       // edges per tile
#define M2     (TE * 67)   // float2 count of one m tile (32*134/2)

typedef __bf16 bf16x8 __attribute__((ext_vector_type(8)));
typedef float  f32x16 __attribute__((ext_vector_type(16)));
typedef float  f32x4  __attribute__((ext_vector_type(4)));

__device__ __forceinline__ unsigned short f32_bf16_rne(float x) {
    union { float f; unsigned u; } v; v.f = x;
    unsigned u = v.u;
    u += 0x7FFFu + ((u >> 16) & 1u);
    return (unsigned short)(u >> 16);
}
__device__ __forceinline__ float bf16_f32(unsigned short h) {
    union { float f; unsigned u; } v; v.u = ((unsigned)h) << 16;
    return v.f;
}
// trunc split: a = hi + lo, |err| ~ 2^-17 |a|
__device__ __forceinline__ void split_pack(float a, float b, unsigned& ph, unsigned& pl) {
    unsigned ua = __float_as_uint(a), ub = __float_as_uint(b);
    ph = (ua >> 16) | (ub & 0xffff0000u);
    float ra = a - __uint_as_float(ua & 0xffff0000u);
    float rb = b - __uint_as_float(ub & 0xffff0000u);
    pl = (__float_as_uint(ra) >> 16) | (__float_as_uint(rb) & 0xffff0000u);
}
__device__ __forceinline__ bf16x8 upack(unsigned a, unsigned b, unsigned c, unsigned d) {
    union { unsigned u[4]; bf16x8 v; } t;
    t.u[0] = a; t.u[1] = b; t.u[2] = c; t.u[3] = d;
    return t.v;
}

// ---------------------------------------------------------------------------
// prep: pack weights into FRAGMENT-MAJOR layout (5 groups incl. tail group 4)
// ---------------------------------------------------------------------------
__global__ __launch_bounds__(256) void prep_kernel(
    const float* __restrict__ Wm, const float* __restrict__ bm,
    const float* __restrict__ We, const float* __restrict__ fw,
    unsigned short* __restrict__ WF, unsigned short* __restrict__ WeF,
    unsigned short* __restrict__ FwF)
{
    int i = blockIdx.x * 256 + threadIdx.x;
    if (i < CHPAD * KPAD) {                                  // W_m (+bias col)
        int c = i / KPAD, k = i - c * KPAD;
        float v = 0.f;
        if (c < CAT) {
            if (k < CAT) v = Wm[c * CAT + k];
            else if (k == CAT) v = bm[c];
        }
        unsigned short h = f32_bf16_rne(v);
        unsigned short l = f32_bf16_rne(v - bf16_f32(h));
        int wv = c >> 5, l31 = c & 31, ks = k >> 4;
        int lane = ((k >> 3) & 1) * 32 + l31, j = k & 7;
        size_t idx = ((size_t)(wv * 9 + ks) * 64 + lane) * 16 + j;
        WF[idx] = h; WF[idx + 8] = l;
    } else if (i < CHPAD * KPAD + CHPAD * 16) {              // W_e (K -> 16)
        int j2 = i - CHPAD * KPAD; int c = j2 >> 4, r = j2 & 15;
        float v = (c < CAT && r < NRBF) ? We[c * NRBF + r] : 0.f;
        unsigned short h = f32_bf16_rne(v);
        unsigned short l = f32_bf16_rne(v - bf16_f32(h));
        int wv = c >> 5, l31 = c & 31;
        int lane = (r >> 3) * 32 + l31, j = r & 7;
        size_t idx = ((size_t)wv * 64 + lane) * 16 + j;
        WeF[idx] = h; WeF[idx + 8] = l;
    } else if (i < CHPAD * KPAD + CHPAD * 16 + 16 * CHPAD) { // final_w (16 rows)
        int j3 = i - CHPAD * KPAD - CHPAD * 16;
        int r = j3 / CHPAD, c = j3 - r * CHPAD;
        float v = (r < NRBF && c < CAT) ? fw[r * CAT + c] : 0.f;
        unsigned short h = f32_bf16_rne(v);
        unsigned short l = f32_bf16_rne(v - bf16_f32(h));
        int wv = c >> 5, kk = c & 31;
        int lane = (kk >> 3) * 16 + r, j = kk & 7;
        size_t idx = ((size_t)wv * 64 + lane) * 16 + j;
        FwF[idx] = h; FwF[idx + 8] = l;
    }
}

// ---------------------------------------------------------------------------
// angle: s_a = dot(a_sbf[a,:], colsum(W_a)), scatter-add into sum_s[kj]
// ---------------------------------------------------------------------------
__global__ __launch_bounds__(256) void angle_kernel(
    const float* __restrict__ a_sbf, const int* __restrict__ kj_idx,
    const float* __restrict__ W_a, float* __restrict__ sum_s, int A)
{
    __shared__ float wsum[ADIM];
    int tid = threadIdx.x;
    if (tid < ADIM) {
        float s = 0.f;
        #pragma unroll
        for (int b = 0; b < NBIL; ++b) s += W_a[b * ADIM + tid];
        wsum[tid] = s;
    }
    __syncthreads();

    int a = blockIdx.x * 256 + tid;
    if (a >= A) return;

    const float* row = a_sbf + (size_t)a * ADIM;
    float s = 0.f;
    #pragma unroll
    for (int d2 = 0; d2 < ADIM / 2; ++d2) {
        float2 v = *reinterpret_cast<const float2*>(row + d2 * 2);
        s += v.x * wsum[d2 * 2] + v.y * wsum[d2 * 2 + 1];
    }
    atomicAdd(&sum_s[kj_idx[a]], s);
}

// Zero-instruction opaque pin (R7-validated).
#define PIN_WEIGHTS()                                                          \
    asm volatile("" :                                                         \
        "+v"(wfh[0]), "+v"(wfh[1]), "+v"(wfh[2]), "+v"(wfh[3]), "+v"(wfh[4]), \
        "+v"(wfh[5]), "+v"(wfh[6]), "+v"(wfh[7]), "+v"(wfh[8]),               \
        "+v"(wfl[0]), "+v"(wfl[1]), "+v"(wfl[2]), "+v"(wfl[3]), "+v"(wfl[4]), \
        "+v"(wfl[5]), "+v"(wfl[6]), "+v"(wfl[7]), "+v"(wfl[8]),               \
        "+v"(weh), "+v"(wel), "+v"(fwh), "+v"(fwl))

#define MF32(AC, W, B) AC = __builtin_amdgcn_mfma_f32_32x32x16_bf16(W, B, AC, 0, 0, 0)

// ---------------------------------------------------------------------------
// edge: R12 structure (best: 135 us) + MFMA1 split into TWO strictly
// alternating accumulator chains (main and tail) so dependent-MFMA latency is
// half-hidden even at 2 waves/SIMD. +16 AGPR stays in the 256-reg bucket ->
// occupancy unchanged. 2 barriers/tile, plain stores.
// ---------------------------------------------------------------------------
__global__ __launch_bounds__(256, 2) void edge_kernel(
    const float* __restrict__ m_ji, const float* __restrict__ e_rbf,
    const float* __restrict__ We_raw,
    const unsigned short* __restrict__ WF, const unsigned short* __restrict__ WeF,
    const unsigned short* __restrict__ FwF,
    const float* __restrict__ sum_s, float* __restrict__ out, int E, int NT)
{
    __shared__ unsigned short mhs[TE][MSTR];    //  9728 B
    __shared__ unsigned short mls[TE][MSTR];    //  9728 B
    __shared__ unsigned short maeh[TE][TSTR];   // 10752 B (proj overlaid)
    __shared__ unsigned short mael[TE][TSTR];   // 10752 B
    __shared__ unsigned short wf4s[9][64][16];  // 18432 B  -> 59392 B total

    const int tid = threadIdx.x;
    const int l   = tid & 63;
    const int wv  = __builtin_amdgcn_readfirstlane(tid >> 6);  // 0..3
    const int l31 = l & 31;
    const int hi5 = l >> 5;
    const int GD  = gridDim.x;

    // ---- resident weight fragments for this wave's main group ------------
    bf16x8 wfh[9], wfl[9];
    #pragma unroll
    for (int ks = 0; ks < 9; ++ks) {
        const unsigned short* p = WF + ((size_t)(wv * 9 + ks) * 64 + l) * 16;
        wfh[ks] = *reinterpret_cast<const bf16x8*>(p);
        wfl[ks] = *reinterpret_cast<const bf16x8*>(p + 8);
    }
    const unsigned short* pe = WeF + ((size_t)wv * 64 + l) * 16;
    bf16x8 weh = *reinterpret_cast<const bf16x8*>(pe);
    bf16x8 wel = *reinterpret_cast<const bf16x8*>(pe + 8);
    const unsigned short* pf = FwF + ((size_t)wv * 64 + l) * 16;
    bf16x8 fwh = *reinterpret_cast<const bf16x8*>(pf);
    bf16x8 fwl = *reinterpret_cast<const bf16x8*>(pf + 8);
    PIN_WEIGHTS();

    // ---- stage tail group-4 A-fragments into LDS (once) ------------------
    {
        const uint4* src = reinterpret_cast<const uint4*>(WF + (size_t)(4 * 9) * 64 * 16);
        uint4* dst = reinterpret_cast<uint4*>(&wf4s[0][0][0]);
        for (int f = tid; f < 9 * 64 * 2; f += 256)   // 1152 x 16B
            dst[f] = src[f];
    }

    // ---- wave-uniform W_e scalars for tail te (rows 128..133) -> SGPRs ---
    float we4[6][6];
    #pragma unroll
    for (int r0 = 0; r0 < 6; ++r0)
        #pragma unroll
        for (int r = 0; r < 6; ++r)
            we4[r0][r] = We_raw[(size_t)(128 + r0) * NRBF + r];

    // ---- one-time LDS init: m bias/pad cols 134..143 ---------------------
    if (tid < 160) {
        int r = tid / 5, j = tid - r * 5;
        *reinterpret_cast<unsigned*>(&mhs[r][134 + 2 * j]) = (j == 0) ? 0x00003F80u : 0u;
        *reinterpret_cast<unsigned*>(&mls[r][134 + 2 * j]) = 0u;
    }

    // ---- per-lane prefetch state -----------------------------------------
    float2 mpre[9];
    float2 er01, er23, er45;
    float  ssp;

#define LOADM(T)                                                              \
    do { int tt = (T);                                                        \
        const float2* mb = reinterpret_cast<const float2*>(m_ji + (size_t)tt * TE * CAT); \
        int nv2 = min(TE, E - tt * TE) * 67;                                  \
        _Pragma("unroll")                                                     \
        for (int i_ = 0; i_ < 9; ++i_) {                                      \
            int f_ = tid + i_ * 256;                                          \
            mpre[i_] = (f_ < nv2) ? mb[f_] : make_float2(0.f, 0.f);           \
        }                                                                     \
    } while (0)

#define LOADE(T)                                                              \
    do { int tt = (T);                                                        \
        er01 = make_float2(0.f, 0.f); er23 = er01; er45 = er01;               \
        int e_ = tt * TE + l31;                                               \
        if (e_ < E) {                                                         \
            const float* ep_ = e_rbf + (size_t)e_ * NRBF;                     \
            er01 = *reinterpret_cast<const float2*>(ep_);                     \
            er23 = *reinterpret_cast<const float2*>(ep_ + 2);                 \
            er45 = *reinterpret_cast<const float2*>(ep_ + 4);                 \
        }                                                                     \
    } while (0)

#define LOADSS(T)                                                             \
    do { int tt = (T);                                                        \
        ssp = 0.f;                                                            \
        if (tid < 192) {                                                      \
            int eo_ = tt * TE + tid / 6;                                      \
            if (eo_ < E) ssp = sum_s[eo_];                                    \
        }                                                                     \
    } while (0)

    // ---- prologue: prefetch tile t0 ---------------------------------------
    {
        int t0 = blockIdx.x;
        LOADM(t0); LOADE(t0); LOADSS(t0);
    }

    int it = 0;
    for (int t = blockIdx.x; t < NT; t += GD, ++it) {
        const int e0 = t * TE;
        PIN_WEIGHTS();

        // ---- latch this tile's er (tail te) + ss; build eb frags ---------
        float er_s0 = er01.x, er_s1 = er01.y, er_s2 = er23.x,
              er_s3 = er23.y, er_s4 = er45.x, er_s5 = er45.y;
        const float ss_cur = ssp;
        bf16x8 ebh, ebl;
        {
            unsigned h0, h1, h2, q0, q1, q2;
            split_pack(er01.x, er01.y, h0, q0);
            split_pack(er23.x, er23.y, h1, q1);
            split_pack(er45.x, er45.y, h2, q2);
            if (hi5) { h0 = h1 = h2 = q0 = q1 = q2 = 0; }   // k 8..15 pad
            ebh = upack(h0, h1, h2, 0);
            ebl = upack(q0, q1, q2, 0);
        }

        // ---- stage m tile -> split-bf16 LDS (once per value) -------------
        #pragma unroll
        for (int i = 0; i < 9; ++i) {
            int f = tid + i * 256;
            if (f < M2) {
                int r = f / 67, c = f - r * 67;
                unsigned h, lo2; split_pack(mpre[i].x, mpre[i].y, h, lo2);
                *reinterpret_cast<unsigned*>(&mhs[r][2 * c]) = h;
                *reinterpret_cast<unsigned*>(&mls[r][2 * c]) = lo2;
            }
        }
        __syncthreads();   // barrier A: tile staged

        // ---- issue next tile's global loads (ride under MFMA) ------------
        if (t + GD < NT) { LOADM(t + GD); LOADE(t + GD); LOADSS(t + GD); }

        // ---- MFMA1 main: TWO alternating acc chains ----------------------
        f32x16 accA = {0,0,0,0,0,0,0,0,0,0,0,0,0,0,0,0};
        f32x16 accB = {0,0,0,0,0,0,0,0,0,0,0,0,0,0,0,0};
        f32x16 acct = {0,0,0,0,0,0,0,0,0,0,0,0,0,0,0,0};
        #pragma unroll
        for (int ks = 0; ks < 9; ++ks) {
            bf16x8 bh = *reinterpret_cast<const bf16x8*>(&mhs[l31][ks * 16 + hi5 * 8]);
            bf16x8 bl = *reinterpret_cast<const bf16x8*>(&mls[l31][ks * 16 + hi5 * 8]);
            if (ks & 1) {
                MF32(accB, wfh[ks], bh); MF32(accA, wfl[ks], bh); MF32(accB, wfh[ks], bl);
            } else {
                MF32(accA, wfh[ks], bh); MF32(accB, wfl[ks], bh); MF32(accA, wfh[ks], bl);
            }
        }
        acct = __builtin_amdgcn_mfma_f32_32x32x16_bf16(weh, ebh, acct, 0, 0, 0);
        acct = __builtin_amdgcn_mfma_f32_32x32x16_bf16(wel, ebh, acct, 0, 0, 0);
        acct = __builtin_amdgcn_mfma_f32_32x32x16_bf16(weh, ebl, acct, 0, 0, 0);

        // ---- mae main = silu(x)*te -> wave-private LDS slice -------------
        #pragma unroll
        for (int q = 0; q < 4; ++q) {
            float mz[4];
            #pragma unroll
            for (int i = 0; i < 4; ++i) {
                float x  = accA[q * 4 + i] + accB[q * 4 + i];
                float sg = x / (1.f + __expf(-x));
                mz[i] = sg * acct[q * 4 + i];
            }
            unsigned h0, h1, q0, q1;
            split_pack(mz[0], mz[1], h0, q0);
            split_pack(mz[2], mz[3], h1, q1);
            const int cq = 32 * wv + 8 * q + 4 * hi5;
            *reinterpret_cast<uint2*>(&maeh[l31][cq]) = make_uint2(h0, h1);
            *reinterpret_cast<uint2*>(&mael[l31][cq]) = make_uint2(q0, q1);
        }

        // ---- MFMA3 main: own slice -> overlay [es][32wv..] ---------------
        #pragma unroll
        for (int nt = 0; nt < 2; ++nt) {
            f32x4 a3 = {0, 0, 0, 0};
            const int mr = nt * 16 + (l & 15);
            bf16x8 bh = *reinterpret_cast<const bf16x8*>(&maeh[mr][32 * wv + (l >> 4) * 8]);
            bf16x8 bl = *reinterpret_cast<const bf16x8*>(&mael[mr][32 * wv + (l >> 4) * 8]);
            a3 = __builtin_amdgcn_mfma_f32_16x16x32_bf16(fwh, bh, a3, 0, 0, 0);
            a3 = __builtin_amdgcn_mfma_f32_16x16x32_bf16(fwl, bh, a3, 0, 0, 0);
            a3 = __builtin_amdgcn_mfma_f32_16x16x32_bf16(fwh, bl, a3, 0, 0, 0);
            const int g4 = l >> 4, es = nt * 16 + (l & 15);
            if (g4 == 0) {
                *reinterpret_cast<f32x4*>(&maeh[es][32 * wv]) = a3;
            } else if (g4 == 1) {
                *reinterpret_cast<float*>(&maeh[es][32 * wv + 8])  = a3[0];
                *reinterpret_cast<float*>(&maeh[es][32 * wv + 10]) = a3[1];
            }
        }

        // ---- TAIL group 4 (channels 128-133), one rotating wave ----------
        if (wv == ((blockIdx.x + it) & 3)) {
            const unsigned short* pf4 = FwF + ((size_t)4 * 64 + l) * 16;
            bf16x8 fw4h = *reinterpret_cast<const bf16x8*>(pf4);
            bf16x8 fw4l = *reinterpret_cast<const bf16x8*>(pf4 + 8);

            f32x16 ac4A = {0,0,0,0,0,0,0,0,0,0,0,0,0,0,0,0};
            f32x16 ac4B = {0,0,0,0,0,0,0,0,0,0,0,0,0,0,0,0};
            #pragma unroll
            for (int ks = 0; ks < 9; ++ks) {   // A-frags from LDS (pipelined)
                bf16x8 a4h = *reinterpret_cast<const bf16x8*>(&wf4s[ks][l][0]);
                bf16x8 a4l = *reinterpret_cast<const bf16x8*>(&wf4s[ks][l][8]);
                bf16x8 bh = *reinterpret_cast<const bf16x8*>(&mhs[l31][ks * 16 + hi5 * 8]);
                bf16x8 bl = *reinterpret_cast<const bf16x8*>(&mls[l31][ks * 16 + hi5 * 8]);
                if (ks & 1) {
                    MF32(ac4B, a4h, bh); MF32(ac4A, a4l, bh); MF32(ac4B, a4h, bl);
                } else {
                    MF32(ac4A, a4h, bh); MF32(ac4B, a4l, bh); MF32(ac4A, a4h, bl);
                }
            }
            // te4 in fp32 VALU: reg i covers row (i&3)+8(i>>2)+4hi5
            float te4[4];
            #pragma unroll
            for (int i = 0; i < 4; ++i) {
                float dlo = er_s0 * we4[i][0] + er_s1 * we4[i][1] + er_s2 * we4[i][2]
                          + er_s3 * we4[i][3] + er_s4 * we4[i][4] + er_s5 * we4[i][5];
                float dhi = 0.f;
                if (i < 2)
                    dhi = er_s0 * we4[4 + i][0] + er_s1 * we4[4 + i][1] + er_s2 * we4[4 + i][2]
                        + er_s3 * we4[4 + i][3] + er_s4 * we4[4 + i][4] + er_s5 * we4[4 + i][5];
                te4[i] = hi5 ? dhi : dlo;
            }
            // mae4: only q==0 regs have nonzero te (rows 0-5); rest zero
            {
                float mz[4];
                #pragma unroll
                for (int i = 0; i < 4; ++i) {
                    float x  = ac4A[i] + ac4B[i];
                    float sg = x / (1.f + __expf(-x));
                    mz[i] = sg * te4[i];
                }
                unsigned h0, h1, q0, q1;
                split_pack(mz[0], mz[1], h0, q0);
                split_pack(mz[2], mz[3], h1, q1);
                const int cq = 128 + 4 * hi5;
                *reinterpret_cast<uint2*>(&maeh[l31][cq]) = make_uint2(h0, h1);
                *reinterpret_cast<uint2*>(&mael[l31][cq]) = make_uint2(q0, q1);
                #pragma unroll
                for (int q = 1; q < 4; ++q) {
                    *reinterpret_cast<uint2*>(&maeh[l31][128 + 8 * q + 4 * hi5]) = make_uint2(0, 0);
                    *reinterpret_cast<uint2*>(&mael[l31][128 + 8 * q + 4 * hi5]) = make_uint2(0, 0);
                }
            }
            // tail MFMA3 -> overlay [es][128..]
            #pragma unroll
            for (int nt = 0; nt < 2; ++nt) {
                f32x4 a3 = {0, 0, 0, 0};
                const int mr = nt * 16 + (l & 15);
                bf16x8 bh = *reinterpret_cast<const bf16x8*>(&maeh[mr][128 + (l >> 4) * 8]);
                bf16x8 bl = *reinterpret_cast<const bf16x8*>(&mael[mr][128 + (l >> 4) * 8]);
                a3 = __builtin_amdgcn_mfma_f32_16x16x32_bf16(fw4h, bh, a3, 0, 0, 0);
                a3 = __builtin_amdgcn_mfma_f32_16x16x32_bf16(fw4l, bh, a3, 0, 0, 0);
                a3 = __builtin_amdgcn_mfma_f32_16x16x32_bf16(fw4h, bl, a3, 0, 0, 0);
                const int g4 = l >> 4, es = nt * 16 + (l & 15);
                if (g4 == 0) {
                    *reinterpret_cast<f32x4*>(&maeh[es][128]) = a3;
                } else if (g4 == 1) {
                    *reinterpret_cast<float*>(&maeh[es][128 + 8])  = a3[0];
                    *reinterpret_cast<float*>(&maeh[es][128 + 10]) = a3[1];
                }
            }
        }
        __syncthreads();   // barrier B: all overlays complete

        // ---- cross-group reduce + scale + store --------------------------
        if (tid < 192) {
            const int es = tid / 6, r = tid - es * 6;
            const int eo = e0 + es;
            if (eo < E) {
                float vsum = 0.f;
                #pragma unroll
                for (int w2 = 0; w2 < 5; ++w2)
                    vsum += *reinterpret_cast<const float*>(&maeh[es][32 * w2 + 2 * r]);
                out[(size_t)eo * NRBF + r] = vsum * ss_cur;
            }
        }
    }
#undef LOADM
#undef LOADE
#undef LOADSS
}

// ---------------------------------------------------------------------------
extern "C" void kernel_launch(void* const* d_in, const int* in_sizes, int n_in,
                              void* d_out, int out_size, void* d_ws, size_t ws_size,
                              hipStream_t stream)
{
    const float* m_ji    = (const float*)d_in[0];
    // d_in[1] nbr_list, d_in[2] angle_list: unused by the reference math
    const float* e_rbf   = (const float*)d_in[3];
    const float* a_sbf   = (const float*)d_in[4];
    const int*   kj_idx  = (const int*)  d_in[5];
    const float* W_m     = (const float*)d_in[6];
    const float* b_m     = (const float*)d_in[7];
    const float* W_e     = (const float*)d_in[8];
    const float* W_a     = (const float*)d_in[9];
    const float* final_w = (const float*)d_in[10];
    float* out = (float*)d_out;

    const int E  = in_sizes[0] / CAT;
    const int A  = in_sizes[5];
    const int NT = (E + TE - 1) / TE;

    // workspace layout
    char* ws = (char*)d_ws;
    float* sum_s = (float*)ws;
    size_t off = ((size_t)E * 4 + 255) & ~(size_t)255;
    unsigned short* WF  = (unsigned short*)(ws + off); off += (size_t)5 * 9 * 64 * 16 * 2;
    unsigned short* WeF = (unsigned short*)(ws + off); off += (size_t)5 * 64 * 16 * 2;
    unsigned short* FwF = (unsigned short*)(ws + off); off += (size_t)5 * 64 * 16 * 2;

    hipMemsetAsync(sum_s, 0, (size_t)E * sizeof(float), stream);

    const int prep_n = CHPAD * KPAD + CHPAD * 16 + 16 * CHPAD;
    prep_kernel<<<(prep_n + 255) / 256, 256, 0, stream>>>(
        W_m, b_m, W_e, final_w, WF, WeF, FwF);
    angle_kernel<<<(A + 255) / 256, 256, 0, stream>>>(a_sbf, kj_idx, W_a, sum_s, A);

    int grid = 2048; if (grid > NT) grid = NT;
    edge_kernel<<<grid, 256, 0, stream>>>(m_ji, e_rbf, W_e, WF, WeF, FwF,
                                          sum_s, out, E, NT);
}